// Round 9
// baseline (377.546 us; speedup 1.0000x reference)
//
#include <hip/hip_runtime.h>
#include <cstddef>
#include <math.h>

#define L_DIM 2048
#define C_DIM 512
#define CQ_DIM 64
#define B_DIM 8

typedef _Float16 f16x8 __attribute__((ext_vector_type(8)));
typedef __fp16 fp16x2_t __attribute__((ext_vector_type(2)));
typedef float f32x4 __attribute__((ext_vector_type(4)));

__device__ __forceinline__ unsigned short f2h(float f) {
    union { _Float16 h; unsigned short u; } v;
    v.h = (_Float16)f;
    return v.u;
}

// packed fp32x2 -> fp16x2 (RTZ) as uint
__device__ __forceinline__ unsigned p2u(float a, float b) {
    union { fp16x2_t h; unsigned u; } v;
    v.h = __builtin_amdgcn_cvt_pkrtz(a, b);
    return v.u;
}

// ---------------------------------------------------------------------------
// prep_w: Wq/Wk/Wv (fp32 [co][ci][3]) -> Wh fp16 [t][640co][512ci]
// ---------------------------------------------------------------------------
__global__ __launch_bounds__(256) void prep_w(const float* __restrict__ Wq,
                                              const float* __restrict__ Wk,
                                              const float* __restrict__ Wv,
                                              unsigned short* __restrict__ Wh) {
    const int idx = blockIdx.x * 256 + threadIdx.x;
    const int ci = idx & 511;
    const int co = (idx >> 9) % 640;
    const int t  = idx / (640 * 512);
    float w;
    if (co < 64)       w = Wq[(size_t)co * 1536 + ci * 3 + t];
    else if (co < 128) w = Wk[(size_t)(co - 64) * 1536 + ci * 3 + t];
    else               w = Wv[(size_t)(co - 128) * 1536 + ci * 3 + t];
    Wh[idx] = f2h(w);
}

// ---------------------------------------------------------------------------
// prep_x: x fp32 [b][ci][l] -> xT fp16 [b][l][512ci]. 64ci x 64l tile per block.
// ---------------------------------------------------------------------------
__global__ __launch_bounds__(256) void prep_x(const float* __restrict__ x,
                                              unsigned short* __restrict__ xT) {
    const int l0  = blockIdx.x * 64;
    const int ci0 = blockIdx.y * 64;
    const int b   = blockIdx.z;

    __shared__ float xs[64][68];
    const int tid = threadIdx.x;
    const float* xb = x + ((size_t)b * C_DIM + ci0) * L_DIM;

    for (int idx = tid; idx < 64 * 16; idx += 256) {
        int ci = idx >> 4, lq = idx & 15;
        *(float4*)&xs[ci][lq * 4] = *(const float4*)&xb[(size_t)ci * L_DIM + l0 + lq * 4];
    }
    __syncthreads();

    unsigned short* ob = xT + ((size_t)b * L_DIM + l0) * C_DIM + ci0;
    for (int idx = tid; idx < 64 * 8; idx += 256) {
        int l = idx >> 3, c8 = idx & 7;
        ushort4 r0, r1;
        r0.x = f2h(xs[c8 * 8 + 0][l]); r0.y = f2h(xs[c8 * 8 + 1][l]);
        r0.z = f2h(xs[c8 * 8 + 2][l]); r0.w = f2h(xs[c8 * 8 + 3][l]);
        r1.x = f2h(xs[c8 * 8 + 4][l]); r1.y = f2h(xs[c8 * 8 + 5][l]);
        r1.z = f2h(xs[c8 * 8 + 6][l]); r1.w = f2h(xs[c8 * 8 + 7][l]);
        *(ushort4*)&ob[(size_t)l * C_DIM + c8 * 8] = r0;
        *(ushort4*)&ob[(size_t)l * C_DIM + c8 * 8 + 4] = r1;
    }
}

// ---------------------------------------------------------------------------
// conv_all: out[co,l] = sum_t sum_ci Wh[t][co][ci] * x[ci][l+t-1] via MFMA.
// ---------------------------------------------------------------------------
__global__ __launch_bounds__(256) void conv_all(const unsigned short* __restrict__ Wh,
                                                const unsigned short* __restrict__ xT,
                                                unsigned short* __restrict__ qT,
                                                unsigned short* __restrict__ kT,
                                                unsigned short* __restrict__ vB) {
    const int l0  = blockIdx.x * 128;
    const int co0 = blockIdx.y * 64;
    const int b   = blockIdx.z;

    __shared__ unsigned short As[3][64][40];
    __shared__ unsigned short Bs[130][40];

    const int tid  = threadIdx.x;
    const int lane = tid & 63, w = tid >> 6;
    const int ln15 = lane & 15, quad = lane >> 4;

    const int co_w = (w & 1) * 32;
    const int l_w  = (w >> 1) * 64;

    const unsigned short* xb = xT + (size_t)b * L_DIM * C_DIM;

    f32x4 acc[2][4] = {};

    for (int ci0 = 0; ci0 < C_DIM; ci0 += 32) {
        __syncthreads();
        for (int idx = tid; idx < 768; idx += 256) {
            int t = idx >> 8, co = (idx >> 2) & 63, c8 = idx & 3;
            *(float4*)&As[t][co][c8 * 8] =
                *(const float4*)&Wh[(((size_t)t * 640) + co0 + co) * C_DIM + ci0 + c8 * 8];
        }
        for (int idx = tid; idx < 520; idx += 256) {
            int la = idx >> 2, c8 = idx & 3;
            int l = l0 - 1 + la;
            float4 vx = {0.f, 0.f, 0.f, 0.f};
            if (l >= 0 && l < L_DIM)
                vx = *(const float4*)&xb[(size_t)l * C_DIM + ci0 + c8 * 8];
            *(float4*)&Bs[la][c8 * 8] = vx;
        }
        __syncthreads();

#pragma unroll
        for (int t = 0; t < 3; t++) {
            f16x8 a[2], bfr[4];
#pragma unroll
            for (int ct = 0; ct < 2; ct++)
                a[ct] = *(const f16x8*)&As[t][co_w + ct * 16 + ln15][quad * 8];
#pragma unroll
            for (int lt = 0; lt < 4; lt++)
                bfr[lt] = *(const f16x8*)&Bs[l_w + lt * 16 + ln15 + t][quad * 8];
#pragma unroll
            for (int ct = 0; ct < 2; ct++)
#pragma unroll
                for (int lt = 0; lt < 4; lt++)
                    acc[ct][lt] = __builtin_amdgcn_mfma_f32_16x16x32_f16(a[ct], bfr[lt], acc[ct][lt], 0, 0, 0);
        }
    }

    if (co0 < 128) {
        unsigned short* dst = (co0 == 0 ? qT : kT) + (size_t)b * L_DIM * CQ_DIM;
#pragma unroll
        for (int ct = 0; ct < 2; ct++)
#pragma unroll
            for (int lt = 0; lt < 4; lt++) {
                const int l = l0 + l_w + lt * 16 + ln15;
                ushort4 r;
                r.x = f2h(acc[ct][lt][0]); r.y = f2h(acc[ct][lt][1]);
                r.z = f2h(acc[ct][lt][2]); r.w = f2h(acc[ct][lt][3]);
                *(ushort4*)&dst[(size_t)l * CQ_DIM + co_w + ct * 16 + quad * 4] = r;
            }
    } else {
        unsigned short* dst = vB + ((size_t)b * C_DIM + (co0 - 128)) * L_DIM;
#pragma unroll
        for (int ct = 0; ct < 2; ct++)
#pragma unroll
            for (int lt = 0; lt < 4; lt++) {
                const int l = l0 + l_w + lt * 16 + ln15;
#pragma unroll
                for (int r = 0; r < 4; r++) {
                    const int co = co_w + ct * 16 + quad * 4 + r;
                    dst[(size_t)co * L_DIM + l] = f2h(acc[ct][lt][r]);
                }
            }
    }
}

// ---------------------------------------------------------------------------
// Fused attention, online softmax, WAVE-LOCAL j ownership:
//  Block tile 64j x 128co, 4 waves. Wave w owns j group w*16 for BOTH the
//  scores/softmax phase and the PV phase (O[128co x 16j]). pps is wave-private
//  (no barrier between softmax and PV); alpha & l stay in registers.
//  2 barriers/iter (minimal K-loop) + register prefetch of next Q/V tiles.
// Grid (32 j, 4 co, 8 b) = 1024 blocks = 4 blocks/CU.
// ---------------------------------------------------------------------------
__global__ __launch_bounds__(256, 4) void pv_k(const unsigned short* __restrict__ qT,
                                               const unsigned short* __restrict__ kT,
                                               const unsigned short* __restrict__ vB,
                                               const float* __restrict__ gamma,
                                               float* __restrict__ out) {
    const int j0  = blockIdx.x * 64;
    const int co0 = blockIdx.y * 128;
    const int b   = blockIdx.z;

    __shared__ unsigned short qTs[64 * 68];   // [i][c]; also initial kT stage
    __shared__ unsigned short vvs[128 * 68];  // [co][i]
    __shared__ unsigned short pps[64 * 72];   // [j][i], wave-private 16-row slabs

    const int tid = threadIdx.x;
    const int lane = tid & 63, w = tid >> 6;
    const int ln15 = lane & 15, quad = lane >> 4;

    const unsigned short* qb = qT + (size_t)b * L_DIM * CQ_DIM;
    const unsigned short* kb = kT + (size_t)b * L_DIM * CQ_DIM;
    const unsigned short* vb = vB + (size_t)b * C_DIM * L_DIM;

    const int sj = w * 16;            // this wave's j group (both phases)
    const int j  = sj + ln15;         // this lane's j column

    // ---- stage kT into qTs (temp), hoist K-fragments (8 VGPRs) ----
    for (int idx = tid; idx < 64 * 8; idx += 256) {
        int r = idx >> 3, c8 = idx & 7;
        *(float4*)&qTs[r * 68 + c8 * 8] = *(const float4*)&kb[(size_t)(j0 + r) * CQ_DIM + c8 * 8];
    }
    __syncthreads();
    f16x8 kfr[2];
#pragma unroll
    for (int cc = 0; cc < 2; cc++)
        kfr[cc] = *(const f16x8*)&qTs[(sj + ln15) * 68 + cc * 32 + quad * 8];

    // ---- register prefetch of iter 0 ----
    const int pr = tid >> 3, pc8 = tid & 7;   // staging coords
    float4 pq[2], pv[4];
    {
        const int i0 = 0;
        pq[0] = *(const float4*)&qb[(size_t)(i0 + pr) * CQ_DIM + pc8 * 8];
        pq[1] = *(const float4*)&qb[(size_t)(i0 + pr + 32) * CQ_DIM + pc8 * 8];
#pragma unroll
        for (int k = 0; k < 4; k++)
            pv[k] = *(const float4*)&vb[(size_t)(co0 + pr + k * 32) * L_DIM + i0 + pc8 * 8];
    }

    f32x4 oacc[8] = {};        // O[128co x 16j]: 8 co-tiles
    float m_run = -1e30f;
    float l_run = 0.f;

    for (int i0 = 0; i0 < L_DIM; i0 += 64) {
        __syncthreads();   // prev iter's qTs/vvs reads (and initial kfr read) done
        // ds_write staged tiles from prefetch regs
        *(float4*)&qTs[pr * 68 + pc8 * 8] = pq[0];
        *(float4*)&qTs[(pr + 32) * 68 + pc8 * 8] = pq[1];
#pragma unroll
        for (int k = 0; k < 4; k++)
            *(float4*)&vvs[(pr + k * 32) * 68 + pc8 * 8] = pv[k];
        // prefetch next iter (wrap harmlessly on last)
        {
            int i1 = i0 + 64;
            if (i1 >= L_DIM) i1 = 0;
            pq[0] = *(const float4*)&qb[(size_t)(i1 + pr) * CQ_DIM + pc8 * 8];
            pq[1] = *(const float4*)&qb[(size_t)(i1 + pr + 32) * CQ_DIM + pc8 * 8];
#pragma unroll
            for (int k = 0; k < 4; k++)
                pv[k] = *(const float4*)&vb[(size_t)(co0 + pr + k * 32) * L_DIM + i1 + pc8 * 8];
        }
        __syncthreads();   // stage visible

        // scores: S[64i x 16j] for this wave's j group
        f32x4 sacc[4] = {};
#pragma unroll
        for (int cc = 0; cc < 2; cc++) {
#pragma unroll
            for (int it = 0; it < 4; it++) {
                const f16x8 afr = *(const f16x8*)&qTs[(it * 16 + ln15) * 68 + cc * 32 + quad * 8];
                sacc[it] = __builtin_amdgcn_mfma_f32_16x16x32_f16(afr, kfr[cc], sacc[it], 0, 0, 0);
            }
        }

        // online softmax for this lane's j column (reduce i across quads)
        float bm = -1e30f;
#pragma unroll
        for (int it = 0; it < 4; it++)
#pragma unroll
            for (int r = 0; r < 4; r++)
                bm = fmaxf(bm, sacc[it][r]);
        bm = fmaxf(bm, __shfl_xor(bm, 16, 64));
        bm = fmaxf(bm, __shfl_xor(bm, 32, 64));
        const float m_new = fmaxf(m_run, bm);
        const float alpha = __expf(m_run - m_new);
        m_run = m_new;

        float lsum = 0.f;
#pragma unroll
        for (int it = 0; it < 4; it++) {
            float p0 = __expf(sacc[it][0] - m_new);
            float p1 = __expf(sacc[it][1] - m_new);
            float p2 = __expf(sacc[it][2] - m_new);
            float p3 = __expf(sacc[it][3] - m_new);
            lsum += (p0 + p1) + (p2 + p3);
            uint2 u;
            u.x = p2u(p0, p1);
            u.y = p2u(p2, p3);
            *(uint2*)&pps[j * 72 + it * 16 + quad * 4] = u;
        }
        lsum += __shfl_xor(lsum, 16, 64);
        lsum += __shfl_xor(lsum, 32, 64);
        l_run = l_run * alpha + lsum;

        // PV (same wave consumes its own pps rows; lgkmcnt orders write->read)
        if (__any(alpha < 1.f)) {
#pragma unroll
            for (int t = 0; t < 8; t++)
#pragma unroll
                for (int r = 0; r < 4; r++)
                    oacc[t][r] *= alpha;
        }
#pragma unroll
        for (int cc = 0; cc < 2; cc++) {
            const f16x8 bfrP = *(const f16x8*)&pps[(sj + ln15) * 72 + cc * 32 + quad * 8];
#pragma unroll
            for (int t = 0; t < 8; t++) {
                const f16x8 afrV = *(const f16x8*)&vvs[(t * 16 + ln15) * 68 + cc * 32 + quad * 8];
                oacc[t] = __builtin_amdgcn_mfma_f32_16x16x32_f16(afrV, bfrP, oacc[t], 0, 0, 0);
            }
        }
    }

    // epilogue: normalize by l (in-register, per-lane j) and store
    const float inv = gamma[0] / l_run;
#pragma unroll
    for (int t = 0; t < 8; t++)
#pragma unroll
        for (int r = 0; r < 4; r++) {
            const int co = co0 + t * 16 + quad * 4 + r;
            out[((size_t)b * C_DIM + co) * L_DIM + j0 + j] = oacc[t][r] * inv;
        }
}

// ---------------------------------------------------------------------------
extern "C" void kernel_launch(void* const* d_in, const int* in_sizes, int n_in,
                              void* d_out, int out_size, void* d_ws, size_t ws_size,
                              hipStream_t stream) {
    const float* x     = (const float*)d_in[0];
    const float* Wq    = (const float*)d_in[1];
    const float* Wk    = (const float*)d_in[2];
    const float* Wv    = (const float*)d_in[3];
    const float* gamma = (const float*)d_in[4];
    float* out = (float*)d_out;

    unsigned short* ws_h = (unsigned short*)d_ws;
    unsigned short* qT = ws_h;                        // 8*2048*64   = 1,048,576
    unsigned short* kT = qT + 1048576;
    unsigned short* vB = kT + 1048576;                // 8*512*2048  = 8,388,608
    unsigned short* xT = vB + 8388608;                // 8*2048*512  = 8,388,608
    unsigned short* Wh = xT + 8388608;                // 3*640*512   = 983,040

    prep_w  <<<3840, 256, 0, stream>>>(Wq, Wk, Wv, Wh);
    prep_x  <<<dim3(32, 8, 8), 256, 0, stream>>>(x, xT);
    conv_all<<<dim3(16, 10, 8), 256, 0, stream>>>(Wh, xT, qT, kT, vB);
    pv_k    <<<dim3(32, 4, 8), 256, 0, stream>>>(qT, kT, vB, gamma, out);
}

// Round 10
// 356.638 us; speedup vs baseline: 1.0586x; 1.0586x over previous
//
#include <hip/hip_runtime.h>
#include <cstddef>
#include <math.h>

#define L_DIM 2048
#define C_DIM 512
#define CQ_DIM 64
#define B_DIM 8

typedef _Float16 f16x8 __attribute__((ext_vector_type(8)));
typedef __fp16 fp16x2_t __attribute__((ext_vector_type(2)));
typedef float f32x4 __attribute__((ext_vector_type(4)));

__device__ __forceinline__ unsigned short f2h(float f) {
    union { _Float16 h; unsigned short u; } v;
    v.h = (_Float16)f;
    return v.u;
}

// packed fp32x2 -> fp16x2 (RTZ) as uint
__device__ __forceinline__ unsigned p2u(float a, float b) {
    union { fp16x2_t h; unsigned u; } v;
    v.h = __builtin_amdgcn_cvt_pkrtz(a, b);
    return v.u;
}

// ---------------------------------------------------------------------------
// prep_w: Wq/Wk/Wv (fp32 [co][ci][3]) -> Wh fp16 [t][640co][512ci]
// ---------------------------------------------------------------------------
__global__ __launch_bounds__(256) void prep_w(const float* __restrict__ Wq,
                                              const float* __restrict__ Wk,
                                              const float* __restrict__ Wv,
                                              unsigned short* __restrict__ Wh) {
    const int idx = blockIdx.x * 256 + threadIdx.x;
    const int ci = idx & 511;
    const int co = (idx >> 9) % 640;
    const int t  = idx / (640 * 512);
    float w;
    if (co < 64)       w = Wq[(size_t)co * 1536 + ci * 3 + t];
    else if (co < 128) w = Wk[(size_t)(co - 64) * 1536 + ci * 3 + t];
    else               w = Wv[(size_t)(co - 128) * 1536 + ci * 3 + t];
    Wh[idx] = f2h(w);
}

// ---------------------------------------------------------------------------
// prep_x: x fp32 [b][ci][l] -> xT fp16 [b][l][512ci]. 64ci x 64l tile per block.
// ---------------------------------------------------------------------------
__global__ __launch_bounds__(256) void prep_x(const float* __restrict__ x,
                                              unsigned short* __restrict__ xT) {
    const int l0  = blockIdx.x * 64;
    const int ci0 = blockIdx.y * 64;
    const int b   = blockIdx.z;

    __shared__ float xs[64][68];
    const int tid = threadIdx.x;
    const float* xb = x + ((size_t)b * C_DIM + ci0) * L_DIM;

    for (int idx = tid; idx < 64 * 16; idx += 256) {
        int ci = idx >> 4, lq = idx & 15;
        *(float4*)&xs[ci][lq * 4] = *(const float4*)&xb[(size_t)ci * L_DIM + l0 + lq * 4];
    }
    __syncthreads();

    unsigned short* ob = xT + ((size_t)b * L_DIM + l0) * C_DIM + ci0;
    for (int idx = tid; idx < 64 * 8; idx += 256) {
        int l = idx >> 3, c8 = idx & 7;
        ushort4 r0, r1;
        r0.x = f2h(xs[c8 * 8 + 0][l]); r0.y = f2h(xs[c8 * 8 + 1][l]);
        r0.z = f2h(xs[c8 * 8 + 2][l]); r0.w = f2h(xs[c8 * 8 + 3][l]);
        r1.x = f2h(xs[c8 * 8 + 4][l]); r1.y = f2h(xs[c8 * 8 + 5][l]);
        r1.z = f2h(xs[c8 * 8 + 6][l]); r1.w = f2h(xs[c8 * 8 + 7][l]);
        *(ushort4*)&ob[(size_t)l * C_DIM + c8 * 8] = r0;
        *(ushort4*)&ob[(size_t)l * C_DIM + c8 * 8 + 4] = r1;
    }
}

// ---------------------------------------------------------------------------
// conv_all: out[co,l] = sum_t sum_ci Wh[t][co][ci] * x[ci][l+t-1] via MFMA.
// ---------------------------------------------------------------------------
__global__ __launch_bounds__(256) void conv_all(const unsigned short* __restrict__ Wh,
                                                const unsigned short* __restrict__ xT,
                                                unsigned short* __restrict__ qT,
                                                unsigned short* __restrict__ kT,
                                                unsigned short* __restrict__ vB) {
    const int l0  = blockIdx.x * 128;
    const int co0 = blockIdx.y * 64;
    const int b   = blockIdx.z;

    __shared__ unsigned short As[3][64][40];
    __shared__ unsigned short Bs[130][40];

    const int tid  = threadIdx.x;
    const int lane = tid & 63, w = tid >> 6;
    const int ln15 = lane & 15, quad = lane >> 4;

    const int co_w = (w & 1) * 32;
    const int l_w  = (w >> 1) * 64;

    const unsigned short* xb = xT + (size_t)b * L_DIM * C_DIM;

    f32x4 acc[2][4] = {};

    for (int ci0 = 0; ci0 < C_DIM; ci0 += 32) {
        __syncthreads();
        for (int idx = tid; idx < 768; idx += 256) {
            int t = idx >> 8, co = (idx >> 2) & 63, c8 = idx & 3;
            *(float4*)&As[t][co][c8 * 8] =
                *(const float4*)&Wh[(((size_t)t * 640) + co0 + co) * C_DIM + ci0 + c8 * 8];
        }
        for (int idx = tid; idx < 520; idx += 256) {
            int la = idx >> 2, c8 = idx & 3;
            int l = l0 - 1 + la;
            float4 vx = {0.f, 0.f, 0.f, 0.f};
            if (l >= 0 && l < L_DIM)
                vx = *(const float4*)&xb[(size_t)l * C_DIM + ci0 + c8 * 8];
            *(float4*)&Bs[la][c8 * 8] = vx;
        }
        __syncthreads();

#pragma unroll
        for (int t = 0; t < 3; t++) {
            f16x8 a[2], bfr[4];
#pragma unroll
            for (int ct = 0; ct < 2; ct++)
                a[ct] = *(const f16x8*)&As[t][co_w + ct * 16 + ln15][quad * 8];
#pragma unroll
            for (int lt = 0; lt < 4; lt++)
                bfr[lt] = *(const f16x8*)&Bs[l_w + lt * 16 + ln15 + t][quad * 8];
#pragma unroll
            for (int ct = 0; ct < 2; ct++)
#pragma unroll
                for (int lt = 0; lt < 4; lt++)
                    acc[ct][lt] = __builtin_amdgcn_mfma_f32_16x16x32_f16(a[ct], bfr[lt], acc[ct][lt], 0, 0, 0);
        }
    }

    if (co0 < 128) {
        unsigned short* dst = (co0 == 0 ? qT : kT) + (size_t)b * L_DIM * CQ_DIM;
#pragma unroll
        for (int ct = 0; ct < 2; ct++)
#pragma unroll
            for (int lt = 0; lt < 4; lt++) {
                const int l = l0 + l_w + lt * 16 + ln15;
                ushort4 r;
                r.x = f2h(acc[ct][lt][0]); r.y = f2h(acc[ct][lt][1]);
                r.z = f2h(acc[ct][lt][2]); r.w = f2h(acc[ct][lt][3]);
                *(ushort4*)&dst[(size_t)l * CQ_DIM + co_w + ct * 16 + quad * 4] = r;
            }
    } else {
        unsigned short* dst = vB + ((size_t)b * C_DIM + (co0 - 128)) * L_DIM;
#pragma unroll
        for (int ct = 0; ct < 2; ct++)
#pragma unroll
            for (int lt = 0; lt < 4; lt++) {
                const int l = l0 + l_w + lt * 16 + ln15;
#pragma unroll
                for (int r = 0; r < 4; r++) {
                    const int co = co_w + ct * 16 + quad * 4 + r;
                    dst[(size_t)co * L_DIM + l] = f2h(acc[ct][lt][r]);
                }
            }
    }
}

// ---------------------------------------------------------------------------
// Fused attention, online softmax, wave-local j ownership:
//  Block tile 64j x 128co, 4 waves. Wave w owns j group w*16 for BOTH phases
//  (O[128co x 16j]). pps is wave-private (no barrier between softmax and PV);
//  alpha & l live in registers. 2 barriers/iter, inline global->LDS staging.
// Grid (32 j, 4 co, 8 b) = 1024 blocks = 4 blocks/CU.
// ---------------------------------------------------------------------------
__global__ __launch_bounds__(256) void pv_k(const unsigned short* __restrict__ qT,
                                            const unsigned short* __restrict__ kT,
                                            const unsigned short* __restrict__ vB,
                                            const float* __restrict__ gamma,
                                            float* __restrict__ out) {
    const int j0  = blockIdx.x * 64;
    const int co0 = blockIdx.y * 128;
    const int b   = blockIdx.z;

    __shared__ unsigned short qTs[64 * 68];   // [i][c]; also initial kT stage
    __shared__ unsigned short vvs[128 * 68];  // [co][i]
    __shared__ unsigned short pps[64 * 72];   // [j][i], wave-private 16-row slabs

    const int tid = threadIdx.x;
    const int lane = tid & 63, w = tid >> 6;
    const int ln15 = lane & 15, quad = lane >> 4;

    const unsigned short* qb = qT + (size_t)b * L_DIM * CQ_DIM;
    const unsigned short* kb = kT + (size_t)b * L_DIM * CQ_DIM;
    const unsigned short* vb = vB + (size_t)b * C_DIM * L_DIM;

    const int sj = w * 16;            // this wave's j group (both phases)
    const int j  = sj + ln15;         // this lane's j column

    // ---- stage kT into qTs (temp), hoist K-fragments (8 VGPRs) ----
    for (int idx = tid; idx < 64 * 8; idx += 256) {
        int r = idx >> 3, c8 = idx & 7;
        *(float4*)&qTs[r * 68 + c8 * 8] = *(const float4*)&kb[(size_t)(j0 + r) * CQ_DIM + c8 * 8];
    }
    __syncthreads();
    f16x8 kfr[2];
#pragma unroll
    for (int cc = 0; cc < 2; cc++)
        kfr[cc] = *(const f16x8*)&qTs[(sj + ln15) * 68 + cc * 32 + quad * 8];

    f32x4 oacc[8] = {};        // O[128co x 16j]: 8 co-tiles
    float m_run = -1e30f;
    float l_run = 0.f;

    for (int i0 = 0; i0 < L_DIM; i0 += 64) {
        __syncthreads();   // prev iter's qTs/vvs reads (and initial kfr read) done
        for (int idx = tid; idx < 64 * 8; idx += 256) {
            int r = idx >> 3, c8 = idx & 7;
            *(float4*)&qTs[r * 68 + c8 * 8] = *(const float4*)&qb[(size_t)(i0 + r) * CQ_DIM + c8 * 8];
        }
        for (int idx = tid; idx < 128 * 8; idx += 256) {
            int r = idx >> 3, c8 = idx & 7;
            *(float4*)&vvs[r * 68 + c8 * 8] = *(const float4*)&vb[(size_t)(co0 + r) * L_DIM + i0 + c8 * 8];
        }
        __syncthreads();   // stage visible

        // scores: S[64i x 16j] for this wave's j group
        f32x4 sacc[4] = {};
#pragma unroll
        for (int cc = 0; cc < 2; cc++) {
#pragma unroll
            for (int it = 0; it < 4; it++) {
                const f16x8 afr = *(const f16x8*)&qTs[(it * 16 + ln15) * 68 + cc * 32 + quad * 8];
                sacc[it] = __builtin_amdgcn_mfma_f32_16x16x32_f16(afr, kfr[cc], sacc[it], 0, 0, 0);
            }
        }

        // online softmax for this lane's j column (reduce i across quads)
        float bm = -1e30f;
#pragma unroll
        for (int it = 0; it < 4; it++)
#pragma unroll
            for (int r = 0; r < 4; r++)
                bm = fmaxf(bm, sacc[it][r]);
        bm = fmaxf(bm, __shfl_xor(bm, 16, 64));
        bm = fmaxf(bm, __shfl_xor(bm, 32, 64));
        const float m_new = fmaxf(m_run, bm);
        const float alpha = __expf(m_run - m_new);
        m_run = m_new;

        float lsum = 0.f;
#pragma unroll
        for (int it = 0; it < 4; it++) {
            float p0 = __expf(sacc[it][0] - m_new);
            float p1 = __expf(sacc[it][1] - m_new);
            float p2 = __expf(sacc[it][2] - m_new);
            float p3 = __expf(sacc[it][3] - m_new);
            lsum += (p0 + p1) + (p2 + p3);
            uint2 u;
            u.x = p2u(p0, p1);
            u.y = p2u(p2, p3);
            *(uint2*)&pps[j * 72 + it * 16 + quad * 4] = u;
        }
        lsum += __shfl_xor(lsum, 16, 64);
        lsum += __shfl_xor(lsum, 32, 64);
        l_run = l_run * alpha + lsum;

        // PV (same wave consumes its own pps rows; lgkmcnt orders write->read)
        if (__any(alpha < 1.f)) {
#pragma unroll
            for (int t = 0; t < 8; t++)
#pragma unroll
                for (int r = 0; r < 4; r++)
                    oacc[t][r] *= alpha;
        }
#pragma unroll
        for (int cc = 0; cc < 2; cc++) {
            const f16x8 bfrP = *(const f16x8*)&pps[(sj + ln15) * 72 + cc * 32 + quad * 8];
#pragma unroll
            for (int t = 0; t < 8; t++) {
                const f16x8 afrV = *(const f16x8*)&vvs[(t * 16 + ln15) * 68 + cc * 32 + quad * 8];
                oacc[t] = __builtin_amdgcn_mfma_f32_16x16x32_f16(afrV, bfrP, oacc[t], 0, 0, 0);
            }
        }
    }

    // epilogue: normalize by l (in-register, per-lane j) and store
    const float inv = gamma[0] / l_run;
#pragma unroll
    for (int t = 0; t < 8; t++)
#pragma unroll
        for (int r = 0; r < 4; r++) {
            const int co = co0 + t * 16 + quad * 4 + r;
            out[((size_t)b * C_DIM + co) * L_DIM + j0 + j] = oacc[t][r] * inv;
        }
}

// ---------------------------------------------------------------------------
extern "C" void kernel_launch(void* const* d_in, const int* in_sizes, int n_in,
                              void* d_out, int out_size, void* d_ws, size_t ws_size,
                              hipStream_t stream) {
    const float* x     = (const float*)d_in[0];
    const float* Wq    = (const float*)d_in[1];
    const float* Wk    = (const float*)d_in[2];
    const float* Wv    = (const float*)d_in[3];
    const float* gamma = (const float*)d_in[4];
    float* out = (float*)d_out;

    unsigned short* ws_h = (unsigned short*)d_ws;
    unsigned short* qT = ws_h;                        // 8*2048*64   = 1,048,576
    unsigned short* kT = qT + 1048576;
    unsigned short* vB = kT + 1048576;                // 8*512*2048  = 8,388,608
    unsigned short* xT = vB + 8388608;                // 8*2048*512  = 8,388,608
    unsigned short* Wh = xT + 8388608;                // 3*640*512   = 983,040

    prep_w  <<<3840, 256, 0, stream>>>(Wq, Wk, Wv, Wh);
    prep_x  <<<dim3(32, 8, 8), 256, 0, stream>>>(x, xT);
    conv_all<<<dim3(16, 10, 8), 256, 0, stream>>>(Wh, xT, qT, kT, vB);
    pv_k    <<<dim3(32, 4, 8), 256, 0, stream>>>(qT, kT, vB, gamma, out);
}